// Round 3
// baseline (947.267 us; speedup 1.0000x reference)
//
#include <hip/hip_runtime.h>
#include <hip/hip_bf16.h>

#define NTOK 8192
#define DM 1024
#define DFF 4096
#define NE 8
#define MAXT 136  // max tiles: 8 + 16384/128

typedef __attribute__((ext_vector_type(8))) short bf16x8;
typedef __attribute__((ext_vector_type(4))) float f32x4;

__device__ __forceinline__ ushort f2bf(float f) {
  __hip_bfloat16 h = __float2bfloat16(f);
  return *reinterpret_cast<ushort*>(&h);
}

// ---------------- x fp32 -> bf16 ----------------
__global__ void cvt_x_kernel(const float* __restrict__ x, ushort* __restrict__ xb) {
  int i = blockIdx.x * 256 + threadIdx.x;
  float4 v = reinterpret_cast<const float4*>(x)[i];
  ushort4 o;
  o.x = f2bf(v.x); o.y = f2bf(v.y); o.z = f2bf(v.z); o.w = f2bf(v.w);
  reinterpret_cast<ushort4*>(xb)[i] = o;
}

// ---------- W [R][C] fp32 -> Wt [C][R] bf16, per expert (blockIdx.z) ----------
__global__ void transpose_cvt(const float* __restrict__ in, ushort* __restrict__ out,
                              int R, int C) {
  __shared__ float t[64][65];
  const float* inp = in + (size_t)blockIdx.z * R * C;
  ushort* op = out + (size_t)blockIdx.z * R * C;
  int c0 = blockIdx.x * 64, r0 = blockIdx.y * 64;
  int tid = threadIdx.x;
#pragma unroll
  for (int it = 0; it < 4; ++it) {
    int r = it * 16 + (tid >> 4);
    int c = (tid & 15) * 4;
    float4 v = *reinterpret_cast<const float4*>(inp + (size_t)(r0 + r) * C + c0 + c);
    t[r][c] = v.x; t[r][c + 1] = v.y; t[r][c + 2] = v.z; t[r][c + 3] = v.w;
  }
  __syncthreads();
  int c = tid >> 2, rc = (tid & 3) * 16;
  union { ushort us[16]; uint4 q[2]; } u;
#pragma unroll
  for (int i = 0; i < 16; ++i) u.us[i] = f2bf(t[rc + i][c]);
  uint4* dst = reinterpret_cast<uint4*>(op + (size_t)(c0 + c) * R + r0 + rc);
  dst[0] = u.q[0];
  dst[1] = u.q[1];
}

// ---------------- router ----------------
__global__ void router_kernel(const float* __restrict__ x, const float* __restrict__ router,
                              int* __restrict__ cnt, int* __restrict__ list,
                              float* __restrict__ wa) {
  __shared__ float rl[DM * NE];  // 32 KB
  int tid = threadIdx.x;
  for (int i = tid; i < DM * NE / 4; i += 256)
    reinterpret_cast<float4*>(rl)[i] = reinterpret_cast<const float4*>(router)[i];
  __syncthreads();
  int wave = tid >> 6, lane = tid & 63;
  int tok0 = blockIdx.x * 32 + wave * 8;
  for (int tI = 0; tI < 8; ++tI) {
    int tok = tok0 + tI;
    float acc[NE];
#pragma unroll
    for (int e2 = 0; e2 < NE; ++e2) acc[e2] = 0.f;
    const float4* xr = reinterpret_cast<const float4*>(x + (size_t)tok * DM);
#pragma unroll
    for (int c = 0; c < 4; ++c) {
      float4 v = xr[lane * 4 + c];
      int d = lane * 16 + c * 4;
      const float* vv = reinterpret_cast<const float*>(&v);
#pragma unroll
      for (int q = 0; q < 4; ++q) {
        float xv = vv[q];
#pragma unroll
        for (int e2 = 0; e2 < NE; ++e2) acc[e2] += xv * rl[(d + q) * NE + e2];
      }
    }
    for (int off = 32; off > 0; off >>= 1) {
#pragma unroll
      for (int e2 = 0; e2 < NE; ++e2) acc[e2] += __shfl_xor(acc[e2], off, 64);
    }
    if (lane == 0) {
      int i0 = 0; float v0 = acc[0];
#pragma unroll
      for (int e2 = 1; e2 < NE; ++e2) { if (acc[e2] > v0) { v0 = acc[e2]; i0 = e2; } }
      int i1 = -1; float v1 = -3.4e38f;
#pragma unroll
      for (int e2 = 0; e2 < NE; ++e2) { if (e2 != i0 && acc[e2] > v1) { v1 = acc[e2]; i1 = e2; } }
      float e1 = expf(v1 - v0);
      float w0 = 1.f / (1.f + e1);
      float w1 = e1 / (1.f + e1);
      int s0 = atomicAdd(&cnt[i0], 1);
      list[i0 * NTOK + s0] = tok * 2;
      wa[tok * 2] = w0;
      int s1 = atomicAdd(&cnt[i1], 1);
      list[i1 * NTOK + s1] = tok * 2 + 1;
      wa[tok * 2 + 1] = w1;
    }
  }
}

// ---------------- tile table: flat tile -> (expert, tTile) ----------------
__global__ void build_tiles(const int* __restrict__ cnt, unsigned* __restrict__ table) {
  if (threadIdx.x == 0) {
    int t = 0;
    for (int e = 0; e < NE; ++e) {
      int nt = (cnt[e] + 127) >> 7;
      for (int i = 0; i < nt; ++i) table[t++] = ((unsigned)e << 16) | (unsigned)i;
    }
    for (; t < MAXT; ++t) table[t] = 0xFFFFFFFFu;
  }
}

// ---------------- helpers ----------------
__device__ __forceinline__ void gl_lds16(unsigned long long g, void* s) {
  __builtin_amdgcn_global_load_lds(
      (const __attribute__((address_space(1))) unsigned int*)g,
      (__attribute__((address_space(3))) unsigned int*)s, 16, 0, 0);
}

// ---------------- 3-slot ring sparse expert GEMM ----------------
// 128x256 tile, BK=64 (128B swizzled rows), 8 waves, depth-2 prefetch,
// counted vmcnt (T4), setprio (T5). 6 gl_lds/thread/stage.
template <int PASS>
__launch_bounds__(512, 2)
__global__ void moe_gemm(const ushort* __restrict__ Abase,
                         const ushort* __restrict__ Wt,
                         const int* __restrict__ cnt,
                         const int* __restrict__ list,
                         const unsigned* __restrict__ table,
                         const float* __restrict__ wa,
                         ushort* __restrict__ Hbuf,
                         float* __restrict__ out) {
  constexpr int K = (PASS == 1) ? DM : DFF;
  constexpr int NK = K / 64;
  constexpr int ASLOT = 128 * 128;   // 16 KB
  constexpr int BSLOT = 256 * 128;   // 32 KB

  unsigned td = table[blockIdx.y];
  if (td == 0xFFFFFFFFu) return;  // uniform exit before any barrier
  const int e = td >> 16;
  const int tTile = td & 0xFFFF;
  const int n = cnt[e];
  const int nTile = blockIdx.x;

  __shared__ __attribute__((aligned(16))) char As[3 * ASLOT];
  __shared__ __attribute__((aligned(16))) char Bs[3 * BSLOT];
  __shared__ int aL[128];
  __shared__ unsigned long long pL[128];

  const int tid = threadIdx.x;
  if (tid < 128) {
    int slot = tTile * 128 + tid;
    int sl = (slot < n) ? slot : (n - 1);
    int a = list[e * NTOK + sl];
    aL[tid] = (slot < n) ? a : -1;
    size_t row = (PASS == 1) ? (size_t)(a >> 1) : (size_t)a;
    pL[tid] = (unsigned long long)(Abase + row * K);  // byte address
  }
  __syncthreads();  // drains vmcnt too — clean slate for counted waits

  // staging: 8 threads/row, 16B each; swizzle folded into SOURCE column
  const char* WtE = (const char*)(Wt + (size_t)e * ((size_t)(PASS == 1 ? DFF : DM)) * K);
  const int sr = tid >> 3;             // 0..63
  const int sc = (tid & 7) * 16;       // base byte col
  unsigned long long sA[2], sB[4];
  unsigned dA[2], dB[4];
#pragma unroll
  for (int j = 0; j < 2; ++j) {
    int row = j * 64 + sr;
    sA[j] = pL[row] + (unsigned)(sc ^ ((row & 7) << 4));
    dA[j] = (unsigned)(row * 128 + sc);
  }
#pragma unroll
  for (int j = 0; j < 4; ++j) {
    int row = j * 64 + sr;
    sB[j] = (unsigned long long)WtE + (size_t)(nTile * 256 + row) * (K * 2) +
            (unsigned)(sc ^ ((row & 7) << 4));
    dB[j] = (unsigned)(row * 128 + sc);
  }

  auto STAGE = [&](int s) {
#pragma unroll
    for (int j = 0; j < 2; ++j) { gl_lds16(sA[j], As + s * ASLOT + dA[j]); sA[j] += 128; }
#pragma unroll
    for (int j = 0; j < 4; ++j) { gl_lds16(sB[j], Bs + s * BSLOT + dB[j]); sB[j] += 128; }
  };

  const int wv = tid >> 6, lane = tid & 63;
  const int wm = wv >> 2, wn = wv & 3;

  f32x4 acc[4][4];
#pragma unroll
  for (int m = 0; m < 4; ++m)
#pragma unroll
    for (int nn = 0; nn < 4; ++nn) acc[m][nn] = (f32x4){0.f, 0.f, 0.f, 0.f};

  auto COMPUTE = [&](int s) {
    const char* a_ = As + s * ASLOT;
    const char* b_ = Bs + s * BSLOT;
#pragma unroll
    for (int kk = 0; kk < 2; ++kk) {
      const int kb = kk * 64 + (lane >> 4) * 16;
      bf16x8 af[4], bfr[4];
#pragma unroll
      for (int m = 0; m < 4; ++m) {
        int row = wm * 64 + m * 16 + (lane & 15);
        af[m] = *reinterpret_cast<const bf16x8*>(a_ + row * 128 + (kb ^ ((row & 7) << 4)));
      }
#pragma unroll
      for (int nn = 0; nn < 4; ++nn) {
        int row = wn * 64 + nn * 16 + (lane & 15);
        bfr[nn] = *reinterpret_cast<const bf16x8*>(b_ + row * 128 + (kb ^ ((row & 7) << 4)));
      }
      __builtin_amdgcn_s_setprio(1);
#pragma unroll
      for (int m = 0; m < 4; ++m)
#pragma unroll
        for (int nn = 0; nn < 4; ++nn)
          acc[m][nn] = __builtin_amdgcn_mfma_f32_16x16x32_bf16(af[m], bfr[nn], acc[m][nn], 0, 0, 0);
      __builtin_amdgcn_s_setprio(0);
    }
  };

  STAGE(0);
  STAGE(1);
  int c = 0;
  for (int kt = 0; kt < NK; ++kt) {
    if (kt + 2 < NK) {
      int ss = c + 2; if (ss >= 3) ss -= 3;
      STAGE(ss);
      asm volatile("s_waitcnt vmcnt(12)" ::: "memory");  // retire stage kt, keep 2 in flight
    } else if (kt + 1 < NK) {
      asm volatile("s_waitcnt vmcnt(6)" ::: "memory");
    } else {
      asm volatile("s_waitcnt vmcnt(0)" ::: "memory");
    }
    __builtin_amdgcn_s_barrier();    // all waves see slot kt complete
    asm volatile("" ::: "memory");
    COMPUTE(c);
    asm volatile("" ::: "memory");
    __builtin_amdgcn_s_barrier();    // all waves done reading slot kt (protects overwrite)
    asm volatile("" ::: "memory");
    c = (c == 2) ? 0 : c + 1;
  }

  // epilogue — C/D layout: col = lane&15, row = (lane>>4)*4 + j
#pragma unroll
  for (int m = 0; m < 4; ++m) {
#pragma unroll
    for (int j = 0; j < 4; ++j) {
      int lr = wm * 64 + m * 16 + (lane >> 4) * 4 + j;
      int a = aL[lr];
      if (a < 0) continue;
      if (PASS == 1) {
        ushort* hrow = Hbuf + (size_t)a * DFF + nTile * 256 + wn * 64 + (lane & 15);
#pragma unroll
        for (int nn = 0; nn < 4; ++nn) {
          float v = acc[m][nn][j];
          hrow[nn * 16] = f2bf(v / (1.f + expf(-v)));  // swish
        }
      } else {
        float w = wa[a];
        int tok = a >> 1;
        float* orow = out + (size_t)tok * DM + nTile * 256 + wn * 64 + (lane & 15);
#pragma unroll
        for (int nn = 0; nn < 4; ++nn)
          atomicAdd(&orow[nn * 16], w * acc[m][nn][j]);  // exactly 2 contributions
      }
    }
  }
}

extern "C" void kernel_launch(void* const* d_in, const int* in_sizes, int n_in,
                              void* d_out, int out_size, void* d_ws, size_t ws_size,
                              hipStream_t stream) {
  const float* x = (const float*)d_in[0];
  const float* router = (const float*)d_in[1];
  const float* W1 = (const float*)d_in[2];
  const float* W2 = (const float*)d_in[3];
  float* out = (float*)d_out;
  char* ws = (char*)d_ws;

  size_t off = 0;
  ushort* Xb = (ushort*)(ws + off); off += (size_t)NTOK * DM * 2;          // 16 MB
  ushort* Wt1 = (ushort*)(ws + off); off += (size_t)NE * DM * DFF * 2;     // 64 MB
  ushort* Wt2 = (ushort*)(ws + off); off += (size_t)NE * DM * DFF * 2;     // 64 MB
  ushort* H   = (ushort*)(ws + off); off += (size_t)NTOK * 2 * DFF * 2;    // 128 MB
  int* cnt  = (int*)(ws + off); off += 256;
  int* list = (int*)(ws + off); off += (size_t)NE * NTOK * 4;
  float* wa = (float*)(ws + off); off += (size_t)NTOK * 2 * 4;
  unsigned* table = (unsigned*)(ws + off); off += MAXT * 4;

  hipMemsetAsync(out, 0, (size_t)NTOK * DM * sizeof(float), stream);
  hipMemsetAsync(cnt, 0, NE * sizeof(int), stream);

  cvt_x_kernel<<<NTOK * DM / 4 / 256, 256, 0, stream>>>(x, Xb);
  transpose_cvt<<<dim3(DFF / 64, DM / 64, NE), 256, 0, stream>>>(W1, Wt1, DM, DFF);
  transpose_cvt<<<dim3(DM / 64, DFF / 64, NE), 256, 0, stream>>>(W2, Wt2, DFF, DM);
  router_kernel<<<NTOK / 32, 256, 0, stream>>>(x, router, cnt, list, wa);
  build_tiles<<<1, 64, 0, stream>>>(cnt, table);

  moe_gemm<1><<<dim3(DFF / 256, MAXT), 512, 0, stream>>>(Xb, Wt1, cnt, list, table, wa, H, out);
  moe_gemm<2><<<dim3(DM / 256, MAXT), 512, 0, stream>>>(H, Wt2, cnt, list, table, wa, H, out);
}

// Round 4
// 840.816 us; speedup vs baseline: 1.1266x; 1.1266x over previous
//
#include <hip/hip_runtime.h>
#include <hip/hip_bf16.h>

#define NTOK 8192
#define DM 1024
#define DFF 4096
#define NE 8
#define MAXT 136  // max tiles: 8 + 16384/128

typedef __attribute__((ext_vector_type(8))) short bf16x8;
typedef __attribute__((ext_vector_type(4))) float f32x4;

__device__ __forceinline__ ushort f2bf(float f) {
  __hip_bfloat16 h = __float2bfloat16(f);
  return *reinterpret_cast<ushort*>(&h);
}

// ---------------- x fp32 -> bf16 ----------------
__global__ void cvt_x_kernel(const float* __restrict__ x, ushort* __restrict__ xb) {
  int i = blockIdx.x * 256 + threadIdx.x;
  float4 v = reinterpret_cast<const float4*>(x)[i];
  ushort4 o;
  o.x = f2bf(v.x); o.y = f2bf(v.y); o.z = f2bf(v.z); o.w = f2bf(v.w);
  reinterpret_cast<ushort4*>(xb)[i] = o;
}

// ---------- W [R][C] fp32 -> Wt [C][R] bf16, per expert (blockIdx.z) ----------
__global__ void transpose_cvt(const float* __restrict__ in, ushort* __restrict__ out,
                              int R, int C) {
  __shared__ float t[64][65];
  const float* inp = in + (size_t)blockIdx.z * R * C;
  ushort* op = out + (size_t)blockIdx.z * R * C;
  int c0 = blockIdx.x * 64, r0 = blockIdx.y * 64;
  int tid = threadIdx.x;
#pragma unroll
  for (int it = 0; it < 4; ++it) {
    int r = it * 16 + (tid >> 4);
    int c = (tid & 15) * 4;
    float4 v = *reinterpret_cast<const float4*>(inp + (size_t)(r0 + r) * C + c0 + c);
    t[r][c] = v.x; t[r][c + 1] = v.y; t[r][c + 2] = v.z; t[r][c + 3] = v.w;
  }
  __syncthreads();
  int c = tid >> 2, rc = (tid & 3) * 16;
  union { ushort us[16]; uint4 q[2]; } u;
#pragma unroll
  for (int i = 0; i < 16; ++i) u.us[i] = f2bf(t[rc + i][c]);
  uint4* dst = reinterpret_cast<uint4*>(op + (size_t)(c0 + c) * R + r0 + rc);
  dst[0] = u.q[0];
  dst[1] = u.q[1];
}

// ---------------- router ----------------
__global__ void router_kernel(const float* __restrict__ x, const float* __restrict__ router,
                              int* __restrict__ cnt, int* __restrict__ list,
                              float* __restrict__ wa) {
  __shared__ float rl[DM * NE];  // 32 KB
  int tid = threadIdx.x;
  for (int i = tid; i < DM * NE / 4; i += 256)
    reinterpret_cast<float4*>(rl)[i] = reinterpret_cast<const float4*>(router)[i];
  __syncthreads();
  int wave = tid >> 6, lane = tid & 63;
  int tok0 = blockIdx.x * 32 + wave * 8;
  for (int tI = 0; tI < 8; ++tI) {
    int tok = tok0 + tI;
    float acc[NE];
#pragma unroll
    for (int e2 = 0; e2 < NE; ++e2) acc[e2] = 0.f;
    const float4* xr = reinterpret_cast<const float4*>(x + (size_t)tok * DM);
#pragma unroll
    for (int c = 0; c < 4; ++c) {
      float4 v = xr[lane * 4 + c];
      int d = lane * 16 + c * 4;
      const float* vv = reinterpret_cast<const float*>(&v);
#pragma unroll
      for (int q = 0; q < 4; ++q) {
        float xv = vv[q];
#pragma unroll
        for (int e2 = 0; e2 < NE; ++e2) acc[e2] += xv * rl[(d + q) * NE + e2];
      }
    }
    for (int off = 32; off > 0; off >>= 1) {
#pragma unroll
      for (int e2 = 0; e2 < NE; ++e2) acc[e2] += __shfl_xor(acc[e2], off, 64);
    }
    if (lane == 0) {
      int i0 = 0; float v0 = acc[0];
#pragma unroll
      for (int e2 = 1; e2 < NE; ++e2) { if (acc[e2] > v0) { v0 = acc[e2]; i0 = e2; } }
      int i1 = -1; float v1 = -3.4e38f;
#pragma unroll
      for (int e2 = 0; e2 < NE; ++e2) { if (e2 != i0 && acc[e2] > v1) { v1 = acc[e2]; i1 = e2; } }
      float e1 = expf(v1 - v0);
      float w0 = 1.f / (1.f + e1);
      float w1 = e1 / (1.f + e1);
      int s0 = atomicAdd(&cnt[i0], 1);
      list[i0 * NTOK + s0] = tok * 2;
      wa[tok * 2] = w0;
      int s1 = atomicAdd(&cnt[i1], 1);
      list[i1 * NTOK + s1] = tok * 2 + 1;
      wa[tok * 2 + 1] = w1;
    }
  }
}

// ---------------- tile table: flat tile -> (expert, tTile) ----------------
__global__ void build_tiles(const int* __restrict__ cnt, unsigned* __restrict__ table) {
  if (threadIdx.x == 0) {
    int t = 0;
    for (int e = 0; e < NE; ++e) {
      int nt = (cnt[e] + 127) >> 7;
      for (int i = 0; i < nt; ++i) table[t++] = ((unsigned)e << 16) | (unsigned)i;
    }
    for (; t < MAXT; ++t) table[t] = 0xFFFFFFFFu;
  }
}

// ---------------- helpers ----------------
__device__ __forceinline__ void gl_lds16(unsigned long long g, void* s) {
  __builtin_amdgcn_global_load_lds(
      (const __attribute__((address_space(1))) unsigned int*)g,
      (__attribute__((address_space(3))) unsigned int*)s, 16, 0, 0);
}

#define WAITV0() asm volatile("s_waitcnt vmcnt(0)" ::: "memory")

__device__ __forceinline__ void BARRIER() {
  asm volatile("" ::: "memory");
  __builtin_amdgcn_s_barrier();
  asm volatile("" ::: "memory");
}

// ---------------- sparse expert GEMM: T3-minimum 2-phase template ----------------
// 128x128 tile, BK=64 (128B XOR-swizzled rows), 4 waves, 2-slot double buffer,
// ~66 KB LDS -> 2 blocks/CU (inter-block overlap), STAGE(next) issued BEFORE
// COMPUTE(cur), single vmcnt(0)+barrier per K-step AFTER compute (latency hidden
// under ~1200cy of MFMA). Prologue drains stage 0 before first compute.
template <int PASS>
__launch_bounds__(256, 2)
__global__ void moe_gemm(const ushort* __restrict__ Abase,
                         const ushort* __restrict__ Wt,
                         const int* __restrict__ cnt,
                         const int* __restrict__ list,
                         const unsigned* __restrict__ table,
                         const float* __restrict__ wa,
                         ushort* __restrict__ Hbuf,
                         float* __restrict__ out) {
  constexpr int K = (PASS == 1) ? DM : DFF;
  constexpr int NK = K / 64;
  constexpr int SLOT = 128 * 128;  // 16 KB per operand slot

  unsigned td = table[blockIdx.y];
  if (td == 0xFFFFFFFFu) return;  // uniform exit before any barrier
  const int e = td >> 16;
  const int tTile = td & 0xFFFF;
  const int n = cnt[e];
  const int nTile = blockIdx.x;

  __shared__ __attribute__((aligned(16))) char As[2 * SLOT];
  __shared__ __attribute__((aligned(16))) char Bs[2 * SLOT];
  __shared__ int aL[128];
  __shared__ unsigned long long pL[128];

  const int tid = threadIdx.x;
  if (tid < 128) {
    int slot = tTile * 128 + tid;
    int sl = (slot < n) ? slot : (n - 1);
    int a = list[e * NTOK + sl];
    aL[tid] = (slot < n) ? a : -1;
    size_t row = (PASS == 1) ? (size_t)(a >> 1) : (size_t)a;
    pL[tid] = (unsigned long long)(Abase + row * K);  // byte address
  }
  __syncthreads();

  // staging: 8 threads/row x 16B; 4 row-groups of 32 per operand.
  // swizzle folded into SOURCE column; LDS dest linear (rule 21).
  const char* WtE = (const char*)(Wt + (size_t)e * ((size_t)(PASS == 1 ? DFF : DM)) * K);
  const int sr = tid >> 3;        // 0..31
  const int sc = (tid & 7) * 16;  // base byte col
  unsigned long long sA[4], sB[4];
  unsigned dst[4];
#pragma unroll
  for (int j = 0; j < 4; ++j) {
    int row = j * 32 + sr;
    unsigned swc = (unsigned)(sc ^ ((row & 7) << 4));
    sA[j] = pL[row] + swc;
    sB[j] = (unsigned long long)WtE + (size_t)(nTile * 128 + row) * (K * 2) + swc;
    dst[j] = (unsigned)(row * 128 + sc);
  }

  auto STAGE = [&](int s) {
#pragma unroll
    for (int j = 0; j < 4; ++j) {
      gl_lds16(sA[j], As + s * SLOT + dst[j]);
      gl_lds16(sB[j], Bs + s * SLOT + dst[j]);
      sA[j] += 128;
      sB[j] += 128;
    }
  };

  const int wv = tid >> 6, lane = tid & 63;
  const int r0 = (wv >> 1) * 64, c0 = (wv & 1) * 64;

  f32x4 acc[4][4];
#pragma unroll
  for (int m = 0; m < 4; ++m)
#pragma unroll
    for (int nn = 0; nn < 4; ++nn) acc[m][nn] = (f32x4){0.f, 0.f, 0.f, 0.f};

  auto COMPUTE = [&](int s) {
    const char* a_ = As + s * SLOT;
    const char* b_ = Bs + s * SLOT;
#pragma unroll
    for (int kk = 0; kk < 2; ++kk) {
      const int kb = kk * 32 * 2 + (lane >> 4) * 16;
      bf16x8 af[4], bfr[4];
#pragma unroll
      for (int m = 0; m < 4; ++m) {
        int row = r0 + m * 16 + (lane & 15);
        af[m] = *reinterpret_cast<const bf16x8*>(a_ + row * 128 + (kb ^ ((row & 7) << 4)));
      }
#pragma unroll
      for (int nn = 0; nn < 4; ++nn) {
        int row = c0 + nn * 16 + (lane & 15);
        bfr[nn] = *reinterpret_cast<const bf16x8*>(b_ + row * 128 + (kb ^ ((row & 7) << 4)));
      }
      __builtin_amdgcn_s_setprio(1);
#pragma unroll
      for (int m = 0; m < 4; ++m)
#pragma unroll
        for (int nn = 0; nn < 4; ++nn)
          acc[m][nn] = __builtin_amdgcn_mfma_f32_16x16x32_bf16(af[m], bfr[nn], acc[m][nn], 0, 0, 0);
      __builtin_amdgcn_s_setprio(0);
    }
  };

  // prologue: fill slot 0, drain, barrier
  STAGE(0);
  WAITV0();
  BARRIER();
  // steady state: issue next stage, compute current, drain, barrier
  for (int kt = 0; kt < NK; ++kt) {
    int cur = kt & 1;
    if (kt + 1 < NK) STAGE(cur ^ 1);
    COMPUTE(cur);
    WAITV0();   // next-stage loads had the whole MFMA block to land
    BARRIER();  // all waves done reading cur + see next slot complete
  }

  // epilogue — C/D layout: col = lane&15, row = (lane>>4)*4 + j
#pragma unroll
  for (int m = 0; m < 4; ++m) {
#pragma unroll
    for (int j = 0; j < 4; ++j) {
      int lr = r0 + m * 16 + (lane >> 4) * 4 + j;
      int a = aL[lr];
      if (a < 0) continue;
      if (PASS == 1) {
        ushort* hrow = Hbuf + (size_t)a * DFF + nTile * 128 + c0 + (lane & 15);
#pragma unroll
        for (int nn = 0; nn < 4; ++nn) {
          float v = acc[m][nn][j];
          hrow[nn * 16] = f2bf(v / (1.f + expf(-v)));  // swish
        }
      } else {
        float w = wa[a];
        int tok = a >> 1;
        float* orow = out + (size_t)tok * DM + nTile * 128 + c0 + (lane & 15);
#pragma unroll
        for (int nn = 0; nn < 4; ++nn)
          atomicAdd(&orow[nn * 16], w * acc[m][nn][j]);  // exactly 2 contributions
      }
    }
  }
}

extern "C" void kernel_launch(void* const* d_in, const int* in_sizes, int n_in,
                              void* d_out, int out_size, void* d_ws, size_t ws_size,
                              hipStream_t stream) {
  const float* x = (const float*)d_in[0];
  const float* router = (const float*)d_in[1];
  const float* W1 = (const float*)d_in[2];
  const float* W2 = (const float*)d_in[3];
  float* out = (float*)d_out;
  char* ws = (char*)d_ws;

  size_t off = 0;
  ushort* Xb = (ushort*)(ws + off); off += (size_t)NTOK * DM * 2;          // 16 MB
  ushort* Wt1 = (ushort*)(ws + off); off += (size_t)NE * DM * DFF * 2;     // 64 MB
  ushort* Wt2 = (ushort*)(ws + off); off += (size_t)NE * DM * DFF * 2;     // 64 MB
  ushort* H   = (ushort*)(ws + off); off += (size_t)NTOK * 2 * DFF * 2;    // 128 MB
  int* cnt  = (int*)(ws + off); off += 256;
  int* list = (int*)(ws + off); off += (size_t)NE * NTOK * 4;
  float* wa = (float*)(ws + off); off += (size_t)NTOK * 2 * 4;
  unsigned* table = (unsigned*)(ws + off); off += MAXT * 4;

  hipMemsetAsync(out, 0, (size_t)NTOK * DM * sizeof(float), stream);
  hipMemsetAsync(cnt, 0, NE * sizeof(int), stream);

  cvt_x_kernel<<<NTOK * DM / 4 / 256, 256, 0, stream>>>(x, Xb);
  transpose_cvt<<<dim3(DFF / 64, DM / 64, NE), 256, 0, stream>>>(W1, Wt1, DM, DFF);
  transpose_cvt<<<dim3(DM / 64, DFF / 64, NE), 256, 0, stream>>>(W2, Wt2, DFF, DM);
  router_kernel<<<NTOK / 32, 256, 0, stream>>>(x, router, cnt, list, wa);
  build_tiles<<<1, 64, 0, stream>>>(cnt, table);

  moe_gemm<1><<<dim3(DFF / 128, MAXT), 256, 0, stream>>>(Xb, Wt1, cnt, list, table, wa, H, out);
  moe_gemm<2><<<dim3(DM / 128, MAXT), 256, 0, stream>>>(H, Wt2, cnt, list, table, wa, H, out);
}